// Round 1
// baseline (245.568 us; speedup 1.0000x reference)
//
#include <hip/hip_runtime.h>
#include <math.h>

// ---------------------------------------------------------------------------
// HROMAttention: x(4,2048,512) -> QKV(+bias) -> RoPE -> MHA(8 heads, d=64)
//                -> proj(+bias). All GEMMs bf16 MFMA 16x16x32, fp32 accum.
// ws layout (bytes):
//   [0)         xb     bf16 8192x512     8388608
//   [8388608)   wqb    bf16 1536x512     1572864
//   [9961472)   wpb    bf16  512x512      524288
//   [10485760)  cosT   f32  2048x32       262144
//   [10747904)  sinT   f32  2048x32       262144
//   [11010048)  Qb     bf16 (b,h,t,d)    8388608   (pre-scaled by 0.125)
//   [19398656)  Kb     bf16 (b,h,t,d)    8388608
//   [27787264)  Vtb    bf16 (b,h,d,t)    8388608
//   [36175872)  attnb  bf16 8192x512     8388608
// total 44564480 B (~42.5 MB) of d_ws
// ---------------------------------------------------------------------------

typedef __attribute__((ext_vector_type(8))) short bf16x8;
typedef __attribute__((ext_vector_type(4))) float floatx4;

__device__ __forceinline__ unsigned short f2bf(float f) {
  unsigned int u = __float_as_uint(f);
  u += 0x7fffu + ((u >> 16) & 1u);   // round-to-nearest-even
  return (unsigned short)(u >> 16);
}

__device__ __forceinline__ void gld_lds16(unsigned short* lds, const unsigned short* g) {
  __builtin_amdgcn_global_load_lds(
      (const __attribute__((address_space(1))) unsigned int*)g,
      (__attribute__((address_space(3))) unsigned int*)lds, 16, 0, 0);
}

// ---------------------------------------------------------------------------
// prep: bf16 conversions + RoPE cos/sin table (fp64 trig for accuracy)
// ---------------------------------------------------------------------------
__global__ __launch_bounds__(256) void prep_kernel(
    const float* __restrict__ x, const float* __restrict__ wq, const float* __restrict__ wp,
    unsigned short* __restrict__ xb, unsigned short* __restrict__ wqb,
    unsigned short* __restrict__ wpb, float* __restrict__ cosT, float* __restrict__ sinT) {
  int i = blockIdx.x * 256 + threadIdx.x;
  if (i < 4194304) {
    xb[i] = f2bf(x[i]);
  } else if (i < 4980736) {
    int j = i - 4194304; wqb[j] = f2bf(wq[j]);
  } else if (i < 5242880) {
    int j = i - 4980736; wpb[j] = f2bf(wp[j]);
  } else if (i < 5308416) {
    int j = i - 5242880;
    int t = j >> 5, f = j & 31;
    double fr = (double)t * pow(10000.0, -(double)f / 32.0);
    cosT[j] = (float)cos(fr);
    sinT[j] = (float)sin(fr);
  }
}

// ---------------------------------------------------------------------------
// QKV GEMM: xb(8192x512) @ wqb(1536x512)^T + bias, epilogue RoPE + scatter
// 128x128 tile, BK=32, 4 waves each 64x64 (4x4 m/n tiles of 16x16)
// ---------------------------------------------------------------------------
__global__ __launch_bounds__(256) void qkv_kernel(
    const unsigned short* __restrict__ xb, const unsigned short* __restrict__ wqb,
    const float* __restrict__ qkv_b, const float* __restrict__ cosT,
    const float* __restrict__ sinT, unsigned short* __restrict__ Qb,
    unsigned short* __restrict__ Kb, unsigned short* __restrict__ Vtb) {
  __shared__ __align__(16) unsigned short As[128 * 32];
  __shared__ __align__(16) unsigned short Bs[128 * 32];
  const int tid = threadIdx.x;
  const int wave = tid >> 6, lane = tid & 63, ln = lane & 15, quad = lane >> 4;
  const int m0 = blockIdx.x * 128, n0 = blockIdx.y * 128;
  const int wr = (wave >> 1) * 64, wc = (wave & 1) * 64;

  floatx4 acc[4][4];
#pragma unroll
  for (int i = 0; i < 4; ++i)
#pragma unroll
    for (int j = 0; j < 4; ++j) acc[i][j] = (floatx4){0.f, 0.f, 0.f, 0.f};

  const int c0 = tid, c1 = tid + 256;
  const int ar0 = c0 >> 2, ak0 = (c0 & 3) * 8;
  const int ar1 = c1 >> 2, ak1 = (c1 & 3) * 8;

  for (int k0 = 0; k0 < 512; k0 += 32) {
    __syncthreads();
    gld_lds16(As + c0 * 8, xb + (size_t)(m0 + ar0) * 512 + k0 + ak0);
    gld_lds16(As + c1 * 8, xb + (size_t)(m0 + ar1) * 512 + k0 + ak1);
    gld_lds16(Bs + c0 * 8, wqb + (size_t)(n0 + ar0) * 512 + k0 + ak0);
    gld_lds16(Bs + c1 * 8, wqb + (size_t)(n0 + ar1) * 512 + k0 + ak1);
    __syncthreads();
    bf16x8 af[4], bfb[4];
#pragma unroll
    for (int mi = 0; mi < 4; ++mi)
      af[mi] = *(const bf16x8*)(As + (wr + mi * 16 + ln) * 32 + quad * 8);
#pragma unroll
    for (int ni = 0; ni < 4; ++ni)
      bfb[ni] = *(const bf16x8*)(Bs + (wc + ni * 16 + ln) * 32 + quad * 8);
#pragma unroll
    for (int mi = 0; mi < 4; ++mi)
#pragma unroll
      for (int ni = 0; ni < 4; ++ni)
        acc[mi][ni] = __builtin_amdgcn_mfma_f32_16x16x32_bf16(af[mi], bfb[ni], acc[mi][ni], 0, 0, 0);
  }

  // epilogue: wave's 64 cols lie in exactly one (mat, head)
  const int colbase = n0 + wc;                    // multiple of 64
  const int mat = colbase >> 9;                   // 0=q 1=k 2=v
  const int h = (colbase & 511) >> 6;
  float bias[4];
#pragma unroll
  for (int ni = 0; ni < 4; ++ni) bias[ni] = qkv_b[colbase + ni * 16 + ln];

  if (mat == 2) {
    // V: store transposed (b,h,d,t); lane holds 4 consecutive t at fixed d
#pragma unroll
    for (int mi = 0; mi < 4; ++mi) {
      int row0 = m0 + wr + mi * 16 + quad * 4;
      int bidx = row0 >> 11, t = row0 & 2047;
#pragma unroll
      for (int ni = 0; ni < 4; ++ni) {
        int d = ni * 16 + ln;
        ushort4 pk;
        pk.x = f2bf(acc[mi][ni][0] + bias[ni]);
        pk.y = f2bf(acc[mi][ni][1] + bias[ni]);
        pk.z = f2bf(acc[mi][ni][2] + bias[ni]);
        pk.w = f2bf(acc[mi][ni][3] + bias[ni]);
        *(ushort4*)(Vtb + ((size_t)(bidx * 8 + h) * 64 + d) * 2048 + t) = pk;
      }
    }
  } else {
    // Q/K: in-register RoPE — pair (d, d+32) = acc tiles (ni, ni+2), same lane
    unsigned short* dst = (mat == 0) ? Qb : Kb;
    const float sc = (mat == 0) ? 0.125f : 1.0f;   // fold 1/sqrt(64) into Q
#pragma unroll
    for (int mi = 0; mi < 4; ++mi) {
#pragma unroll
      for (int r = 0; r < 4; ++r) {
        int row = m0 + wr + mi * 16 + quad * 4 + r;
        int bidx = row >> 11, t = row & 2047;
        const float* cr = cosT + t * 32;
        const float* sr = sinT + t * 32;
        size_t obase = ((size_t)(bidx * 8 + h) * 2048 + t) * 64;
#pragma unroll
        for (int ni = 0; ni < 2; ++ni) {
          int dlo = ni * 16 + ln;
          float cv = cr[dlo], sv = sr[dlo];
          float xlo = acc[mi][ni][r] + bias[ni];
          float xhi = acc[mi][ni + 2][r] + bias[ni + 2];
          dst[obase + dlo]      = f2bf((xlo * cv - xhi * sv) * sc);
          dst[obase + dlo + 32] = f2bf((xhi * cv + xlo * sv) * sc);
        }
      }
    }
  }
}

// ---------------------------------------------------------------------------
// Flash attention: block = 128 Q-rows x one (b,h); 4 waves x 32 rows;
// K-tile = 64. Padded LDS (stride 72) to keep b128 frag reads ~conflict-free.
// ---------------------------------------------------------------------------
__global__ __launch_bounds__(256) void attn_kernel(
    const unsigned short* __restrict__ Qb, const unsigned short* __restrict__ Kb,
    const unsigned short* __restrict__ Vtb, const float* __restrict__ mask,
    unsigned short* __restrict__ attnb) {
  __shared__ __align__(16) unsigned short Ks[64 * 72];
  __shared__ __align__(16) unsigned short Vs[64 * 72];
  __shared__ __align__(16) unsigned short Ps[4 * 32 * 72];

  const int tid = threadIdx.x;
  const int wave = tid >> 6, lane = tid & 63, ln = lane & 15, quad = lane >> 4;
  const int bh = blockIdx.y;
  const int b = bh >> 3, h = bh & 7;
  const int q0 = blockIdx.x * 128;
  const int wrow = q0 + wave * 32;

  const unsigned short* Qhead = Qb + (size_t)bh * 2048 * 64;
  const unsigned short* Khead = Kb + (size_t)bh * 2048 * 64;
  const unsigned short* Vhead = Vtb + (size_t)bh * 64 * 2048;
  unsigned short* Pw = Ps + wave * 32 * 72;

  bf16x8 qf[2][2];
#pragma unroll
  for (int mi = 0; mi < 2; ++mi)
#pragma unroll
    for (int ks = 0; ks < 2; ++ks)
      qf[mi][ks] = *(const bf16x8*)(Qhead + (size_t)(wrow + mi * 16 + ln) * 64 + ks * 32 + quad * 8);

  floatx4 o[2][4];
#pragma unroll
  for (int mi = 0; mi < 2; ++mi)
#pragma unroll
    for (int ni = 0; ni < 4; ++ni) o[mi][ni] = (floatx4){0.f, 0.f, 0.f, 0.f};
  float mrun[2][4], lrun[2][4];
#pragma unroll
  for (int mi = 0; mi < 2; ++mi)
#pragma unroll
    for (int r = 0; r < 4; ++r) { mrun[mi][r] = -INFINITY; lrun[mi][r] = 0.f; }

  for (int k0 = 0; k0 < 2048; k0 += 64) {
    __syncthreads();
    for (int c = tid; c < 512; c += 256) {
      int row = c >> 3, off = (c & 7) * 8;
      uint4 kv = *(const uint4*)(Khead + (size_t)(k0 + row) * 64 + off);
      *(uint4*)(Ks + row * 72 + off) = kv;
      uint4 vv = *(const uint4*)(Vhead + (size_t)row * 2048 + k0 + off);
      *(uint4*)(Vs + row * 72 + off) = vv;
    }
    __syncthreads();

    // S = Q K^T (Q pre-scaled)
    floatx4 s[2][4];
#pragma unroll
    for (int ni = 0; ni < 4; ++ni) {
      bf16x8 kf0 = *(const bf16x8*)(Ks + (ni * 16 + ln) * 72 + quad * 8);
      bf16x8 kf1 = *(const bf16x8*)(Ks + (ni * 16 + ln) * 72 + 32 + quad * 8);
#pragma unroll
      for (int mi = 0; mi < 2; ++mi) {
        floatx4 a = (floatx4){0.f, 0.f, 0.f, 0.f};
        a = __builtin_amdgcn_mfma_f32_16x16x32_bf16(qf[mi][0], kf0, a, 0, 0, 0);
        a = __builtin_amdgcn_mfma_f32_16x16x32_bf16(qf[mi][1], kf1, a, 0, 0, 0);
        s[mi][ni] = a;
      }
    }
    // + mask[b, kcol]
#pragma unroll
    for (int ni = 0; ni < 4; ++ni) {
      float mv = mask[b * 2048 + k0 + ni * 16 + ln];
#pragma unroll
      for (int mi = 0; mi < 2; ++mi)
#pragma unroll
        for (int r = 0; r < 4; ++r) s[mi][ni][r] += mv;
    }
    // online softmax
    float al[2][4];
#pragma unroll
    for (int mi = 0; mi < 2; ++mi)
#pragma unroll
      for (int r = 0; r < 4; ++r) {
        float v = fmaxf(fmaxf(s[mi][0][r], s[mi][1][r]), fmaxf(s[mi][2][r], s[mi][3][r]));
        v = fmaxf(v, __shfl_xor(v, 1));
        v = fmaxf(v, __shfl_xor(v, 2));
        v = fmaxf(v, __shfl_xor(v, 4));
        v = fmaxf(v, __shfl_xor(v, 8));
        float nm = fmaxf(mrun[mi][r], v);
        float a = __expf(mrun[mi][r] - nm);
        mrun[mi][r] = nm; lrun[mi][r] *= a; al[mi][r] = a;
      }
#pragma unroll
    for (int mi = 0; mi < 2; ++mi)
#pragma unroll
      for (int ni = 0; ni < 4; ++ni)
#pragma unroll
        for (int r = 0; r < 4; ++r) s[mi][ni][r] = __expf(s[mi][ni][r] - mrun[mi][r]);
#pragma unroll
    for (int mi = 0; mi < 2; ++mi)
#pragma unroll
      for (int r = 0; r < 4; ++r) {
        float sv = s[mi][0][r] + s[mi][1][r] + s[mi][2][r] + s[mi][3][r];
        sv += __shfl_xor(sv, 1);
        sv += __shfl_xor(sv, 2);
        sv += __shfl_xor(sv, 4);
        sv += __shfl_xor(sv, 8);
        lrun[mi][r] += sv;
      }
#pragma unroll
    for (int mi = 0; mi < 2; ++mi)
#pragma unroll
      for (int ni = 0; ni < 4; ++ni)
#pragma unroll
        for (int r = 0; r < 4; ++r) o[mi][ni][r] *= al[mi][r];
    // P -> LDS (C/D layout -> A layout round trip)
#pragma unroll
    for (int mi = 0; mi < 2; ++mi)
#pragma unroll
      for (int ni = 0; ni < 4; ++ni)
#pragma unroll
        for (int r = 0; r < 4; ++r)
          Pw[(mi * 16 + quad * 4 + r) * 72 + ni * 16 + ln] = f2bf(s[mi][ni][r]);
    // O += P V
#pragma unroll
    for (int ks = 0; ks < 2; ++ks) {
      bf16x8 pa[2];
#pragma unroll
      for (int mi = 0; mi < 2; ++mi)
        pa[mi] = *(const bf16x8*)(Pw + (mi * 16 + ln) * 72 + ks * 32 + quad * 8);
#pragma unroll
      for (int ni = 0; ni < 4; ++ni) {
        bf16x8 vf = *(const bf16x8*)(Vs + (ni * 16 + ln) * 72 + ks * 32 + quad * 8);
#pragma unroll
        for (int mi = 0; mi < 2; ++mi)
          o[mi][ni] = __builtin_amdgcn_mfma_f32_16x16x32_bf16(pa[mi], vf, o[mi][ni], 0, 0, 0);
      }
    }
  }
  // epilogue: normalize, write attn (b,t,h*64+d) bf16
#pragma unroll
  for (int mi = 0; mi < 2; ++mi)
#pragma unroll
    for (int r = 0; r < 4; ++r) {
      float inv = 1.f / lrun[mi][r];
      int t = wrow + mi * 16 + quad * 4 + r;
      size_t base = ((size_t)b * 2048 + t) * 512 + h * 64;
#pragma unroll
      for (int ni = 0; ni < 4; ++ni)
        attnb[base + ni * 16 + ln] = f2bf(o[mi][ni][r] * inv);
    }
}

// ---------------------------------------------------------------------------
// proj GEMM: attnb(8192x512) @ wpb(512x512)^T + bias -> out fp32
// ---------------------------------------------------------------------------
__global__ __launch_bounds__(256) void proj_kernel(
    const unsigned short* __restrict__ ab, const unsigned short* __restrict__ wpb,
    const float* __restrict__ proj_b, float* __restrict__ out) {
  __shared__ __align__(16) unsigned short As[128 * 32];
  __shared__ __align__(16) unsigned short Bs[128 * 32];
  const int tid = threadIdx.x;
  const int wave = tid >> 6, lane = tid & 63, ln = lane & 15, quad = lane >> 4;
  const int m0 = blockIdx.x * 128, n0 = blockIdx.y * 128;
  const int wr = (wave >> 1) * 64, wc = (wave & 1) * 64;

  floatx4 acc[4][4];
#pragma unroll
  for (int i = 0; i < 4; ++i)
#pragma unroll
    for (int j = 0; j < 4; ++j) acc[i][j] = (floatx4){0.f, 0.f, 0.f, 0.f};

  const int c0 = tid, c1 = tid + 256;
  const int ar0 = c0 >> 2, ak0 = (c0 & 3) * 8;
  const int ar1 = c1 >> 2, ak1 = (c1 & 3) * 8;

  for (int k0 = 0; k0 < 512; k0 += 32) {
    __syncthreads();
    gld_lds16(As + c0 * 8, ab + (size_t)(m0 + ar0) * 512 + k0 + ak0);
    gld_lds16(As + c1 * 8, ab + (size_t)(m0 + ar1) * 512 + k0 + ak1);
    gld_lds16(Bs + c0 * 8, wpb + (size_t)(n0 + ar0) * 512 + k0 + ak0);
    gld_lds16(Bs + c1 * 8, wpb + (size_t)(n0 + ar1) * 512 + k0 + ak1);
    __syncthreads();
    bf16x8 af[4], bfb[4];
#pragma unroll
    for (int mi = 0; mi < 4; ++mi)
      af[mi] = *(const bf16x8*)(As + (wr + mi * 16 + ln) * 32 + quad * 8);
#pragma unroll
    for (int ni = 0; ni < 4; ++ni)
      bfb[ni] = *(const bf16x8*)(Bs + (wc + ni * 16 + ln) * 32 + quad * 8);
#pragma unroll
    for (int mi = 0; mi < 4; ++mi)
#pragma unroll
      for (int ni = 0; ni < 4; ++ni)
        acc[mi][ni] = __builtin_amdgcn_mfma_f32_16x16x32_bf16(af[mi], bfb[ni], acc[mi][ni], 0, 0, 0);
  }

#pragma unroll
  for (int mi = 0; mi < 4; ++mi)
#pragma unroll
    for (int ni = 0; ni < 4; ++ni) {
      int col = n0 + wc + ni * 16 + ln;
      float pb = proj_b[col];
#pragma unroll
      for (int r = 0; r < 4; ++r) {
        int row = m0 + wr + mi * 16 + quad * 4 + r;
        out[(size_t)row * 512 + col] = acc[mi][ni][r] + pb;
      }
    }
}

// ---------------------------------------------------------------------------
extern "C" void kernel_launch(void* const* d_in, const int* in_sizes, int n_in,
                              void* d_out, int out_size, void* d_ws, size_t ws_size,
                              hipStream_t stream) {
  const float* x      = (const float*)d_in[0];
  const float* mask   = (const float*)d_in[1];
  const float* qkv_w  = (const float*)d_in[2];
  const float* qkv_b  = (const float*)d_in[3];
  const float* proj_w = (const float*)d_in[4];
  const float* proj_b = (const float*)d_in[5];
  float* out = (float*)d_out;

  char* ws = (char*)d_ws;
  unsigned short* xb   = (unsigned short*)(ws);
  unsigned short* wqb  = (unsigned short*)(ws + 8388608);
  unsigned short* wpb  = (unsigned short*)(ws + 9961472);
  float* cosT          = (float*)(ws + 10485760);
  float* sinT          = (float*)(ws + 10747904);
  unsigned short* Qb   = (unsigned short*)(ws + 11010048);
  unsigned short* Kb   = (unsigned short*)(ws + 19398656);
  unsigned short* Vtb  = (unsigned short*)(ws + 27787264);
  unsigned short* attnb= (unsigned short*)(ws + 36175872);

  prep_kernel<<<20736, 256, 0, stream>>>(x, qkv_w, proj_w, xb, wqb, wpb, cosT, sinT);
  dim3 g1(64, 12);
  qkv_kernel<<<g1, 256, 0, stream>>>(xb, wqb, qkv_b, cosT, sinT, Qb, Kb, Vtb);
  dim3 g2(16, 32);
  attn_kernel<<<g2, 256, 0, stream>>>(Qb, Kb, Vtb, mask, attnb);
  dim3 g3(64, 4);
  proj_kernel<<<g3, 256, 0, stream>>>(attnb, wpb, proj_b, out);
}

// Round 2
// 212.040 us; speedup vs baseline: 1.1581x; 1.1581x over previous
//
#include <hip/hip_runtime.h>
#include <math.h>

// ---------------------------------------------------------------------------
// HROMAttention: x(4,2048,512) -> QKV(+bias) -> RoPE -> MHA(8 heads, d=64)
//                -> proj(+bias). All GEMMs bf16 MFMA 16x16x32, fp32 accum.
// Round 2: transposed-flash attention (S^T = K·Q^T): shuffles 64->8/iter,
// P-writes 32xu16 -> 8xb64, register-prefetch K/V staging, exp2-domain
// softmax (Q pre-scaled by 0.125*log2e in qkv epilogue).
// ws layout (bytes):
//   [0)         xb     bf16 8192x512     8388608
//   [8388608)   wqb    bf16 1536x512     1572864
//   [9961472)   wpb    bf16  512x512      524288
//   [10485760)  cosT   f32  2048x32       262144
//   [10747904)  sinT   f32  2048x32       262144
//   [11010048)  Qb     bf16 (b,h,t,d)    8388608   (pre-scaled by 0.125*log2e)
//   [19398656)  Kb     bf16 (b,h,t,d)    8388608
//   [27787264)  Vtb    bf16 (b,h,d,t)    8388608
//   [36175872)  attnb  bf16 8192x512     8388608
// total 44564480 B (~42.5 MB) of d_ws
// ---------------------------------------------------------------------------

typedef __attribute__((ext_vector_type(8))) short bf16x8;
typedef __attribute__((ext_vector_type(4))) float floatx4;

#define LOG2E 1.44269504088896f

__device__ __forceinline__ unsigned short f2bf(float f) {
  unsigned int u = __float_as_uint(f);
  u += 0x7fffu + ((u >> 16) & 1u);   // round-to-nearest-even
  return (unsigned short)(u >> 16);
}

__device__ __forceinline__ void gld_lds16(unsigned short* lds, const unsigned short* g) {
  __builtin_amdgcn_global_load_lds(
      (const __attribute__((address_space(1))) unsigned int*)g,
      (__attribute__((address_space(3))) unsigned int*)lds, 16, 0, 0);
}

// ---------------------------------------------------------------------------
// prep: bf16 conversions + RoPE cos/sin table (fp64 trig for accuracy)
// ---------------------------------------------------------------------------
__global__ __launch_bounds__(256) void prep_kernel(
    const float* __restrict__ x, const float* __restrict__ wq, const float* __restrict__ wp,
    unsigned short* __restrict__ xb, unsigned short* __restrict__ wqb,
    unsigned short* __restrict__ wpb, float* __restrict__ cosT, float* __restrict__ sinT) {
  int i = blockIdx.x * 256 + threadIdx.x;
  if (i < 4194304) {
    xb[i] = f2bf(x[i]);
  } else if (i < 4980736) {
    int j = i - 4194304; wqb[j] = f2bf(wq[j]);
  } else if (i < 5242880) {
    int j = i - 4980736; wpb[j] = f2bf(wp[j]);
  } else if (i < 5308416) {
    int j = i - 5242880;
    int t = j >> 5, f = j & 31;
    double fr = (double)t * pow(10000.0, -(double)f / 32.0);
    cosT[j] = (float)cos(fr);
    sinT[j] = (float)sin(fr);
  }
}

// ---------------------------------------------------------------------------
// QKV GEMM: xb(8192x512) @ wqb(1536x512)^T + bias, epilogue RoPE + scatter
// 128x128 tile, BK=32, 4 waves each 64x64 (4x4 m/n tiles of 16x16)
// ---------------------------------------------------------------------------
__global__ __launch_bounds__(256) void qkv_kernel(
    const unsigned short* __restrict__ xb, const unsigned short* __restrict__ wqb,
    const float* __restrict__ qkv_b, const float* __restrict__ cosT,
    const float* __restrict__ sinT, unsigned short* __restrict__ Qb,
    unsigned short* __restrict__ Kb, unsigned short* __restrict__ Vtb) {
  __shared__ __align__(16) unsigned short As[128 * 32];
  __shared__ __align__(16) unsigned short Bs[128 * 32];
  const int tid = threadIdx.x;
  const int wave = tid >> 6, lane = tid & 63, ln = lane & 15, quad = lane >> 4;
  const int m0 = blockIdx.x * 128, n0 = blockIdx.y * 128;
  const int wr = (wave >> 1) * 64, wc = (wave & 1) * 64;

  floatx4 acc[4][4];
#pragma unroll
  for (int i = 0; i < 4; ++i)
#pragma unroll
    for (int j = 0; j < 4; ++j) acc[i][j] = (floatx4){0.f, 0.f, 0.f, 0.f};

  const int c0 = tid, c1 = tid + 256;
  const int ar0 = c0 >> 2, ak0 = (c0 & 3) * 8;
  const int ar1 = c1 >> 2, ak1 = (c1 & 3) * 8;

  for (int k0 = 0; k0 < 512; k0 += 32) {
    __syncthreads();
    gld_lds16(As + c0 * 8, xb + (size_t)(m0 + ar0) * 512 + k0 + ak0);
    gld_lds16(As + c1 * 8, xb + (size_t)(m0 + ar1) * 512 + k0 + ak1);
    gld_lds16(Bs + c0 * 8, wqb + (size_t)(n0 + ar0) * 512 + k0 + ak0);
    gld_lds16(Bs + c1 * 8, wqb + (size_t)(n0 + ar1) * 512 + k0 + ak1);
    __syncthreads();
    bf16x8 af[4], bfb[4];
#pragma unroll
    for (int mi = 0; mi < 4; ++mi)
      af[mi] = *(const bf16x8*)(As + (wr + mi * 16 + ln) * 32 + quad * 8);
#pragma unroll
    for (int ni = 0; ni < 4; ++ni)
      bfb[ni] = *(const bf16x8*)(Bs + (wc + ni * 16 + ln) * 32 + quad * 8);
#pragma unroll
    for (int mi = 0; mi < 4; ++mi)
#pragma unroll
      for (int ni = 0; ni < 4; ++ni)
        acc[mi][ni] = __builtin_amdgcn_mfma_f32_16x16x32_bf16(af[mi], bfb[ni], acc[mi][ni], 0, 0, 0);
  }

  // epilogue: wave's 64 cols lie in exactly one (mat, head)
  const int colbase = n0 + wc;                    // multiple of 64
  const int mat = colbase >> 9;                   // 0=q 1=k 2=v
  const int h = (colbase & 511) >> 6;
  float bias[4];
#pragma unroll
  for (int ni = 0; ni < 4; ++ni) bias[ni] = qkv_b[colbase + ni * 16 + ln];

  if (mat == 2) {
    // V: store transposed (b,h,d,t); lane holds 4 consecutive t at fixed d
#pragma unroll
    for (int mi = 0; mi < 4; ++mi) {
      int row0 = m0 + wr + mi * 16 + quad * 4;
      int bidx = row0 >> 11, t = row0 & 2047;
#pragma unroll
      for (int ni = 0; ni < 4; ++ni) {
        int d = ni * 16 + ln;
        ushort4 pk;
        pk.x = f2bf(acc[mi][ni][0] + bias[ni]);
        pk.y = f2bf(acc[mi][ni][1] + bias[ni]);
        pk.z = f2bf(acc[mi][ni][2] + bias[ni]);
        pk.w = f2bf(acc[mi][ni][3] + bias[ni]);
        *(ushort4*)(Vtb + ((size_t)(bidx * 8 + h) * 64 + d) * 2048 + t) = pk;
      }
    }
  } else {
    // Q/K: in-register RoPE — pair (d, d+32) = acc tiles (ni, ni+2), same lane
    unsigned short* dst = (mat == 0) ? Qb : Kb;
    // fold 1/sqrt(64) AND log2(e) (exp2-domain softmax) into Q
    const float sc = (mat == 0) ? 0.125f * LOG2E : 1.0f;
#pragma unroll
    for (int mi = 0; mi < 4; ++mi) {
#pragma unroll
      for (int r = 0; r < 4; ++r) {
        int row = m0 + wr + mi * 16 + quad * 4 + r;
        int bidx = row >> 11, t = row & 2047;
        const float* cr = cosT + t * 32;
        const float* sr = sinT + t * 32;
        size_t obase = ((size_t)(bidx * 8 + h) * 2048 + t) * 64;
#pragma unroll
        for (int ni = 0; ni < 2; ++ni) {
          int dlo = ni * 16 + ln;
          float cv = cr[dlo], sv = sr[dlo];
          float xlo = acc[mi][ni][r] + bias[ni];
          float xhi = acc[mi][ni + 2][r] + bias[ni + 2];
          dst[obase + dlo]      = f2bf((xlo * cv - xhi * sv) * sc);
          dst[obase + dlo + 32] = f2bf((xhi * cv + xlo * sv) * sc);
        }
      }
    }
  }
}

// ---------------------------------------------------------------------------
// Transposed flash attention: block = 128 q x one (b,h); 4 waves x 32 q;
// K-tile = 64. S^T = K·Q^T so each lane owns one q-column:
//  - row reductions: 15 in-reg ops + 2 shuffles (vs 4 shuffles/row)
//  - P^T -> LDS as packed b64, read back as b128 B-frags
//  - O^T = V^T·P, epilogue 1/l per-lane, packed ushort4 stores
// K/V staged via register prefetch (loads issued at loop top, stored next iter).
// ---------------------------------------------------------------------------
__global__ __launch_bounds__(256) void attn_kernel(
    const unsigned short* __restrict__ Qb, const unsigned short* __restrict__ Kb,
    const unsigned short* __restrict__ Vtb, const float* __restrict__ mask,
    unsigned short* __restrict__ attnb) {
  __shared__ __align__(16) unsigned short Ks[64 * 72];   // (t_k, d)
  __shared__ __align__(16) unsigned short Vs[64 * 72];   // (d, t_k)
  __shared__ __align__(16) unsigned short Ps[128 * 72];  // (q, t_k) per-wave rows

  const int tid = threadIdx.x;
  const int wave = tid >> 6, lane = tid & 63, ln = lane & 15, quad = lane >> 4;
  const int bh = blockIdx.y;
  const int b = bh >> 3, h = bh & 7;
  const int wq0 = blockIdx.x * 128 + wave * 32;

  const unsigned short* Qhead = Qb + (size_t)bh * 2048 * 64;
  const unsigned short* Khead = Kb + (size_t)bh * 2048 * 64;
  const unsigned short* Vhead = Vtb + (size_t)bh * 64 * 2048;

  // Q B-frags, loaded once: B[n=q][k=d]
  bf16x8 qf[2][2];
#pragma unroll
  for (int ni2 = 0; ni2 < 2; ++ni2)
#pragma unroll
    for (int ks = 0; ks < 2; ++ks)
      qf[ni2][ks] = *(const bf16x8*)(Qhead + (size_t)(wq0 + ni2 * 16 + ln) * 64 + ks * 32 + quad * 8);

  floatx4 o[4][2];   // O^T: [d-tile][q-tile]
#pragma unroll
  for (int mi2 = 0; mi2 < 4; ++mi2)
#pragma unroll
    for (int ni2 = 0; ni2 < 2; ++ni2) o[mi2][ni2] = (floatx4){0.f, 0.f, 0.f, 0.f};
  float mrun[2] = {-INFINITY, -INFINITY};
  float lrun[2] = {0.f, 0.f};

  // staging map: thread covers rows srow and srow+32, 8-short chunk soff
  const int srow = tid >> 3, soff = (tid & 7) * 8;
  uint4 kpre0 = *(const uint4*)(Khead + (size_t)srow * 64 + soff);
  uint4 kpre1 = *(const uint4*)(Khead + (size_t)(srow + 32) * 64 + soff);
  uint4 vpre0 = *(const uint4*)(Vhead + (size_t)srow * 2048 + soff);
  uint4 vpre1 = *(const uint4*)(Vhead + (size_t)(srow + 32) * 2048 + soff);

  for (int k0 = 0; k0 < 2048; k0 += 64) {
    __syncthreads();   // prev-iter Ks/Vs reads done
    *(uint4*)(Ks + srow * 72 + soff) = kpre0;
    *(uint4*)(Ks + (srow + 32) * 72 + soff) = kpre1;
    *(uint4*)(Vs + srow * 72 + soff) = vpre0;
    *(uint4*)(Vs + (srow + 32) * 72 + soff) = vpre1;
    __syncthreads();   // staging visible
    if (k0 + 64 < 2048) {   // prefetch next tile; latency hidden by compute
      kpre0 = *(const uint4*)(Khead + (size_t)(k0 + 64 + srow) * 64 + soff);
      kpre1 = *(const uint4*)(Khead + (size_t)(k0 + 64 + srow + 32) * 64 + soff);
      vpre0 = *(const uint4*)(Vhead + (size_t)srow * 2048 + k0 + 64 + soff);
      vpre1 = *(const uint4*)(Vhead + (size_t)(srow + 32) * 2048 + k0 + 64 + soff);
    }

    // S^T = K·Q^T : A=K-frag A[m=t_k][k=d], B=Q. C: row=t_k(quad*4+r), col=q(ln)
    floatx4 sm[4][2];
#pragma unroll
    for (int mi = 0; mi < 4; ++mi) {
      bf16x8 kf0 = *(const bf16x8*)(Ks + (mi * 16 + ln) * 72 + quad * 8);
      bf16x8 kf1 = *(const bf16x8*)(Ks + (mi * 16 + ln) * 72 + 32 + quad * 8);
#pragma unroll
      for (int ni2 = 0; ni2 < 2; ++ni2) {
        floatx4 a = (floatx4){0.f, 0.f, 0.f, 0.f};
        a = __builtin_amdgcn_mfma_f32_16x16x32_bf16(kf0, qf[ni2][0], a, 0, 0, 0);
        a = __builtin_amdgcn_mfma_f32_16x16x32_bf16(kf1, qf[ni2][1], a, 0, 0, 0);
        sm[mi][ni2] = a;
      }
    }
    // + mask (t_k varies over quad*4+r; exp2 domain -> * log2e)
#pragma unroll
    for (int mi = 0; mi < 4; ++mi) {
      float4 mv = *(const float4*)(mask + b * 2048 + k0 + mi * 16 + quad * 4);
      float m0v = mv.x * LOG2E, m1v = mv.y * LOG2E, m2v = mv.z * LOG2E, m3v = mv.w * LOG2E;
#pragma unroll
      for (int ni2 = 0; ni2 < 2; ++ni2) {
        sm[mi][ni2][0] += m0v; sm[mi][ni2][1] += m1v;
        sm[mi][ni2][2] += m2v; sm[mi][ni2][3] += m3v;
      }
    }
    // online softmax: per lane one q-column -> 16 in-reg + 2 shuffles
    float alpha[2];
#pragma unroll
    for (int ni2 = 0; ni2 < 2; ++ni2) {
      float vmax = sm[0][ni2][0];
#pragma unroll
      for (int mi = 0; mi < 4; ++mi)
#pragma unroll
        for (int r = 0; r < 4; ++r) vmax = fmaxf(vmax, sm[mi][ni2][r]);
      vmax = fmaxf(vmax, __shfl_xor(vmax, 16));
      vmax = fmaxf(vmax, __shfl_xor(vmax, 32));
      float nm = fmaxf(mrun[ni2], vmax);
      alpha[ni2] = exp2f(mrun[ni2] - nm);
      mrun[ni2] = nm;
    }
    float psum[2] = {0.f, 0.f};
#pragma unroll
    for (int mi = 0; mi < 4; ++mi)
#pragma unroll
      for (int ni2 = 0; ni2 < 2; ++ni2)
#pragma unroll
        for (int r = 0; r < 4; ++r) {
          float p = exp2f(sm[mi][ni2][r] - mrun[ni2]);
          sm[mi][ni2][r] = p;
          psum[ni2] += p;
        }
#pragma unroll
    for (int ni2 = 0; ni2 < 2; ++ni2) {
      float s = psum[ni2];
      s += __shfl_xor(s, 16);
      s += __shfl_xor(s, 32);
      lrun[ni2] = lrun[ni2] * alpha[ni2] + s;
    }
#pragma unroll
    for (int mi2 = 0; mi2 < 4; ++mi2)
#pragma unroll
      for (int ni2 = 0; ni2 < 2; ++ni2) {
        o[mi2][ni2][0] *= alpha[ni2]; o[mi2][ni2][1] *= alpha[ni2];
        o[mi2][ni2][2] *= alpha[ni2]; o[mi2][ni2][3] *= alpha[ni2];
      }
    // P^T -> LDS (q, t_k): packed b64, per-wave region, no barrier needed
#pragma unroll
    for (int mi = 0; mi < 4; ++mi)
#pragma unroll
      for (int ni2 = 0; ni2 < 2; ++ni2) {
        ushort4 pk;
        pk.x = f2bf(sm[mi][ni2][0]); pk.y = f2bf(sm[mi][ni2][1]);
        pk.z = f2bf(sm[mi][ni2][2]); pk.w = f2bf(sm[mi][ni2][3]);
        *(ushort4*)(Ps + (wq0 - blockIdx.x * 128 + ni2 * 16 + ln) * 72 + mi * 16 + quad * 4) = pk;
      }
    // O^T += V^T·P : A=Vt-frag A[m=d][k=t_k], B=P-frag B[n=q][k=t_k]
#pragma unroll
    for (int ks = 0; ks < 2; ++ks) {
      bf16x8 pb[2];
#pragma unroll
      for (int ni2 = 0; ni2 < 2; ++ni2)
        pb[ni2] = *(const bf16x8*)(Ps + (wave * 32 + ni2 * 16 + ln) * 72 + ks * 32 + quad * 8);
#pragma unroll
      for (int mi2 = 0; mi2 < 4; ++mi2) {
        bf16x8 vf = *(const bf16x8*)(Vs + (mi2 * 16 + ln) * 72 + ks * 32 + quad * 8);
#pragma unroll
        for (int ni2 = 0; ni2 < 2; ++ni2)
          o[mi2][ni2] = __builtin_amdgcn_mfma_f32_16x16x32_bf16(vf, pb[ni2], o[mi2][ni2], 0, 0, 0);
      }
    }
  }

  // epilogue: O^T lane owns q-col (1/l per-lane), 4 consecutive d per store
#pragma unroll
  for (int ni2 = 0; ni2 < 2; ++ni2) {
    float inv = 1.f / lrun[ni2];
    int t = wq0 + ni2 * 16 + ln;
    size_t base = ((size_t)b * 2048 + t) * 512 + h * 64;
#pragma unroll
    for (int mi2 = 0; mi2 < 4; ++mi2) {
      ushort4 pk;
      pk.x = f2bf(o[mi2][ni2][0] * inv); pk.y = f2bf(o[mi2][ni2][1] * inv);
      pk.z = f2bf(o[mi2][ni2][2] * inv); pk.w = f2bf(o[mi2][ni2][3] * inv);
      *(ushort4*)(attnb + base + mi2 * 16 + quad * 4) = pk;
    }
  }
}

// ---------------------------------------------------------------------------
// proj GEMM: attnb(8192x512) @ wpb(512x512)^T + bias -> out fp32
// ---------------------------------------------------------------------------
__global__ __launch_bounds__(256) void proj_kernel(
    const unsigned short* __restrict__ ab, const unsigned short* __restrict__ wpb,
    const float* __restrict__ proj_b, float* __restrict__ out) {
  __shared__ __align__(16) unsigned short As[128 * 32];
  __shared__ __align__(16) unsigned short Bs[128 * 32];
  const int tid = threadIdx.x;
  const int wave = tid >> 6, lane = tid & 63, ln = lane & 15, quad = lane >> 4;
  const int m0 = blockIdx.x * 128, n0 = blockIdx.y * 128;
  const int wr = (wave >> 1) * 64, wc = (wave & 1) * 64;

  floatx4 acc[4][4];
#pragma unroll
  for (int i = 0; i < 4; ++i)
#pragma unroll
    for (int j = 0; j < 4; ++j) acc[i][j] = (floatx4){0.f, 0.f, 0.f, 0.f};

  const int c0 = tid, c1 = tid + 256;
  const int ar0 = c0 >> 2, ak0 = (c0 & 3) * 8;
  const int ar1 = c1 >> 2, ak1 = (c1 & 3) * 8;

  for (int k0 = 0; k0 < 512; k0 += 32) {
    __syncthreads();
    gld_lds16(As + c0 * 8, ab + (size_t)(m0 + ar0) * 512 + k0 + ak0);
    gld_lds16(As + c1 * 8, ab + (size_t)(m0 + ar1) * 512 + k0 + ak1);
    gld_lds16(Bs + c0 * 8, wpb + (size_t)(n0 + ar0) * 512 + k0 + ak0);
    gld_lds16(Bs + c1 * 8, wpb + (size_t)(n0 + ar1) * 512 + k0 + ak1);
    __syncthreads();
    bf16x8 af[4], bfb[4];
#pragma unroll
    for (int mi = 0; mi < 4; ++mi)
      af[mi] = *(const bf16x8*)(As + (wr + mi * 16 + ln) * 32 + quad * 8);
#pragma unroll
    for (int ni = 0; ni < 4; ++ni)
      bfb[ni] = *(const bf16x8*)(Bs + (wc + ni * 16 + ln) * 32 + quad * 8);
#pragma unroll
    for (int mi = 0; mi < 4; ++mi)
#pragma unroll
      for (int ni = 0; ni < 4; ++ni)
        acc[mi][ni] = __builtin_amdgcn_mfma_f32_16x16x32_bf16(af[mi], bfb[ni], acc[mi][ni], 0, 0, 0);
  }

#pragma unroll
  for (int mi = 0; mi < 4; ++mi)
#pragma unroll
    for (int ni = 0; ni < 4; ++ni) {
      int col = n0 + wc + ni * 16 + ln;
      float pb = proj_b[col];
#pragma unroll
      for (int r = 0; r < 4; ++r) {
        int row = m0 + wr + mi * 16 + quad * 4 + r;
        out[(size_t)row * 512 + col] = acc[mi][ni][r] + pb;
      }
    }
}

// ---------------------------------------------------------------------------
extern "C" void kernel_launch(void* const* d_in, const int* in_sizes, int n_in,
                              void* d_out, int out_size, void* d_ws, size_t ws_size,
                              hipStream_t stream) {
  const float* x      = (const float*)d_in[0];
  const float* mask   = (const float*)d_in[1];
  const float* qkv_w  = (const float*)d_in[2];
  const float* qkv_b  = (const float*)d_in[3];
  const float* proj_w = (const float*)d_in[4];
  const float* proj_b = (const float*)d_in[5];
  float* out = (float*)d_out;

  char* ws = (char*)d_ws;
  unsigned short* xb   = (unsigned short*)(ws);
  unsigned short* wqb  = (unsigned short*)(ws + 8388608);
  unsigned short* wpb  = (unsigned short*)(ws + 9961472);
  float* cosT          = (float*)(ws + 10485760);
  float* sinT          = (float*)(ws + 10747904);
  unsigned short* Qb   = (unsigned short*)(ws + 11010048);
  unsigned short* Kb   = (unsigned short*)(ws + 19398656);
  unsigned short* Vtb  = (unsigned short*)(ws + 27787264);
  unsigned short* attnb= (unsigned short*)(ws + 36175872);

  prep_kernel<<<20736, 256, 0, stream>>>(x, qkv_w, proj_w, xb, wqb, wpb, cosT, sinT);
  dim3 g1(64, 12);
  qkv_kernel<<<g1, 256, 0, stream>>>(xb, wqb, qkv_b, cosT, sinT, Qb, Kb, Vtb);
  dim3 g2(16, 32);
  attn_kernel<<<g2, 256, 0, stream>>>(Qb, Kb, Vtb, mask, attnb);
  dim3 g3(64, 4);
  proj_kernel<<<g3, 256, 0, stream>>>(attnb, wpb, proj_b, out);
}